// Round 2
// baseline (16.967 us; speedup 1.0000x reference)
//
#include <hip/hip_runtime.h>
#include <math.h>

// Problem constants (match reference).
constexpr int Bn = 1024;   // batch
constexpr int Fn = 512;    // features
constexpr int Kn = 16;     // factor dim
constexpr int BPB = 2;     // batches per block

// p2[b] = sum_k sum_q sum_r WX[32k+q][r] * T_k(16q+r),
//   WX[f,k] = x[f]*W[f,k],  T_k(j) = sum_{f>=j} WX[f,k]
// Split T_k(16q+r) = Tq_k(q+1) + S_k(q,r):
//   S_k(q,r)  = sum_{u=r..15} x[16q+u]*W[16q+u][k]     <- x: contiguous float4
//                                                         W^T: batch-invariant regs
//   Tq_k(q+1) = suffix over coarse block sums G_k[q]=S_k(q,0), 32-lane shfl scan
// Thread t = 32k+q owns consumer (k,q) AND row f=t:
//   part = xs*( sum_r wr[r]*S_r  +  Tq*sum_r wr[r]  +  lin_w[t] ),  xs=x[b][t]
// No per-batch LDS transpose at all: W^T gathered once per block into registers.
__global__ __launch_bounds__(512, 4) void fm_kernel(
    const float* __restrict__ x,      // (B,F)
    const float* __restrict__ W,      // (F,K)
    const float* __restrict__ lin_w,  // (1,F)
    const float* __restrict__ lin_b,  // (1,)
    float* __restrict__ out)          // (B,1)
{
    const int t = threadIdx.x;   // == row f this thread owns
    const int k = t >> 5;        // column this thread consumes
    const int q = t & 31;        // coarse 16-row block index
    const int b0 = blockIdx.x * BPB;

    __shared__ float red[BPB][8];

    // ---- batch-invariant: W row (contiguous float4) + W^T column slice ----
    const float4* Wrow4 = reinterpret_cast<const float4*>(W + t * Kn);
    const float4 a0 = Wrow4[0], a1 = Wrow4[1], a2 = Wrow4[2], a3 = Wrow4[3];
    const float wr[16] = {a0.x, a0.y, a0.z, a0.w, a1.x, a1.y, a1.z, a1.w,
                          a2.x, a2.y, a2.z, a2.w, a3.x, a3.y, a3.z, a3.w};

    float wt[16];                 // wt[u] = W[16q+u][k]  (one-time strided gather, L2-hit)
    #pragma unroll
    for (int u = 0; u < 16; ++u)
        wt[u] = W[(16 * q + u) * Kn + k];

    float Wrsum = 0.f;
    #pragma unroll
    for (int r = 0; r < 16; ++r) Wrsum += wr[r];

    const float lw = lin_w[t];

    #pragma unroll
    for (int bb = 0; bb < BPB; ++bb) {
        const float* xb = x + (size_t)(b0 + bb) * Fn;

        // x block q: 16 contiguous floats (4x float4), plus own-row scalar.
        const float4* xq4 = reinterpret_cast<const float4*>(xb + 16 * q);
        const float4 c0 = xq4[0], c1 = xq4[1], c2 = xq4[2], c3 = xq4[3];
        const float xq[16] = {c0.x, c0.y, c0.z, c0.w, c1.x, c1.y, c1.z, c1.w,
                              c2.x, c2.y, c2.z, c2.w, c3.x, c3.y, c3.z, c3.w};
        const float xs = xb[t];

        // Fused suffix + dot: S_r = sum_{u>=r} xq[u]*wt[u]; acc2 = sum_r wr[r]*S_r.
        float S = 0.f, acc2 = 0.f;
        #pragma unroll
        for (int r = 15; r >= 0; --r) {
            S    = fmaf(xq[r], wt[r], S);
            acc2 = fmaf(wr[r], S, acc2);
        }
        const float G = S;   // coarse block sum G_k[q]

        // 32-lane inclusive suffix scan over q -> Tq_k(q+1).
        float incl = G;
        #pragma unroll
        for (int d = 1; d < 32; d <<= 1) {
            const float o = __shfl_down(incl, d, 32);
            if (q + d < 32) incl += o;
        }
        const float Tq = incl - G;

        float part = xs * (acc2 + Tq * Wrsum + lw);

        // Wave butterfly, then one partial per wave.
        #pragma unroll
        for (int d = 32; d >= 1; d >>= 1)
            part += __shfl_xor(part, d);
        if ((t & 63) == 0) red[bb][t >> 6] = part;
    }

    __syncthreads();   // single barrier per block

    if (t < BPB) {
        float tot = red[t][0] + red[t][1] + red[t][2] + red[t][3]
                  + red[t][4] + red[t][5] + red[t][6] + red[t][7];
        tot += lin_b[0];
        out[b0 + t] = 1.0f / (1.0f + expf(-tot));
    }
}

extern "C" void kernel_launch(void* const* d_in, const int* in_sizes, int n_in,
                              void* d_out, int out_size, void* d_ws, size_t ws_size,
                              hipStream_t stream) {
    const float* x     = (const float*)d_in[0];
    const float* W     = (const float*)d_in[1];
    const float* lin_w = (const float*)d_in[2];
    const float* lin_b = (const float*)d_in[3];
    float* out = (float*)d_out;

    hipLaunchKernelGGL(fm_kernel, dim3(Bn / BPB), dim3(512), 0, stream,
                       x, W, lin_w, lin_b, out);
}

// Round 3
// 10.069 us; speedup vs baseline: 1.6852x; 1.6852x over previous
//
#include <hip/hip_runtime.h>
#include <math.h>

// Problem constants (match reference).
constexpr int Bn = 1024;   // batch
constexpr int Fn = 512;    // features
constexpr int Kn = 16;     // factor dim
constexpr int BPB = 2;     // batches per block (interleaved in registers)
constexpr int CSTRIDE = 520;  // swizzled W^T row stride

// p2[b] = sum_{k,q} [ xs * ( sum_u xq[u]*wt[u]*vpre[u]  +  Tq_k(q+1)*Wrsum + lw ) ]
//   thread t = 32k+q owns consumer (k,q) AND row f=t
//   wt[u]   = W[16q+u][k]              (batch-invariant, via one LDS transpose)
//   vpre[u] = sum_{r<=u} W[t][r]       (own-row prefix, batch-invariant)
//   A[u]    = wt[u]*vpre[u]            (precomputed -> per-batch is ONE 16-dot)
//   G       = sum_u xq[u]*wt[u];  Tq = 32-lane suffix-scan of G over q
// All W-derived state computed once per block; per batch: 5 VMEM, 2 tree dots,
// 5 scan shuffles, 6 butterfly shuffles. One barrier per block.
__device__ __forceinline__ float dot16(const float* a, const float* b) {
    float s0 = a[0]*b[0], s1 = a[1]*b[1], s2 = a[2]*b[2], s3 = a[3]*b[3];
    #pragma unroll
    for (int u = 4; u < 16; u += 4) {
        s0 = fmaf(a[u+0], b[u+0], s0);
        s1 = fmaf(a[u+1], b[u+1], s1);
        s2 = fmaf(a[u+2], b[u+2], s2);
        s3 = fmaf(a[u+3], b[u+3], s3);
    }
    return (s0 + s1) + (s2 + s3);
}

__global__ __launch_bounds__(512, 4) void fm_kernel(
    const float* __restrict__ x,      // (B,F)
    const float* __restrict__ W,      // (F,K)
    const float* __restrict__ lin_w,  // (1,F)
    const float* __restrict__ lin_b,  // (1,)
    float* __restrict__ out)          // (B,1)
{
    const int t = threadIdx.x;   // == row f this thread owns
    const int k = t >> 5;        // column this thread consumes
    const int q = t & 31;        // coarse 16-row block index
    const int b0 = blockIdx.x * BPB;

    __shared__ float WT[Kn * CSTRIDE];  // swizzled: WT[k*CSTRIDE + swz(f)] = W[f][k]
    __shared__ float red[BPB][8];

    // ---- one-time setup: W row (coalesced 64B/thread) -> LDS transpose ----
    const float4* Wrow4 = reinterpret_cast<const float4*>(W + t * Kn);
    const float4 a0 = Wrow4[0], a1 = Wrow4[1], a2 = Wrow4[2], a3 = Wrow4[3];
    const float wr[16] = {a0.x, a0.y, a0.z, a0.w, a1.x, a1.y, a1.z, a1.w,
                          a2.x, a2.y, a2.z, a2.w, a3.x, a3.y, a3.z, a3.w};

    const int fs = t ^ (t >> 5);  // swizzle: each bank hit exactly 2x/wave (free)
    #pragma unroll
    for (int kk = 0; kk < Kn; ++kk)
        WT[kk * CSTRIDE + fs] = wr[kk];

    // Own-row prefix sums (VALU, overlaps the LDS writes).
    float vpre[16];
    vpre[0] = wr[0];
    #pragma unroll
    for (int u = 1; u < 16; ++u) vpre[u] = vpre[u - 1] + wr[u];
    const float Wrsum = vpre[15];
    const float lw = lin_w[t];

    __syncthreads();

    // wt[u] = W[16q+u][k]; swizzled read is conflict-free across the 32 q's
    // (low5 of swz(16q+u) = 16(q&1) + (u ^ (q>>1)) -> bijective).
    float wt[16], A[16];
    #pragma unroll
    for (int u = 0; u < 16; ++u) {
        const int f = 16 * q + u;
        wt[u] = WT[k * CSTRIDE + (f ^ (f >> 5))];
    }
    #pragma unroll
    for (int u = 0; u < 16; ++u) A[u] = wt[u] * vpre[u];

    // ---- two batches, fully interleaved for ILP ----
    const float* xa = x + (size_t)b0 * Fn;
    const float* xb = xa + Fn;

    const float4* xa4 = reinterpret_cast<const float4*>(xa + 16 * q);
    const float4* xb4 = reinterpret_cast<const float4*>(xb + 16 * q);
    const float4 ca0 = xa4[0], ca1 = xa4[1], ca2 = xa4[2], ca3 = xa4[3];
    const float4 cb0 = xb4[0], cb1 = xb4[1], cb2 = xb4[2], cb3 = xb4[3];
    const float xqa[16] = {ca0.x, ca0.y, ca0.z, ca0.w, ca1.x, ca1.y, ca1.z, ca1.w,
                           ca2.x, ca2.y, ca2.z, ca2.w, ca3.x, ca3.y, ca3.z, ca3.w};
    const float xqb[16] = {cb0.x, cb0.y, cb0.z, cb0.w, cb1.x, cb1.y, cb1.z, cb1.w,
                           cb2.x, cb2.y, cb2.z, cb2.w, cb3.x, cb3.y, cb3.z, cb3.w};
    const float xsa = xa[t];
    const float xsb = xb[t];

    // Independent tree dots: G (scan input) and acc2 (prefix-folded cross term).
    const float Ga = dot16(xqa, wt);
    const float Gb = dot16(xqb, wt);
    const float Aa = dot16(xqa, A);
    const float Ab = dot16(xqb, A);

    // 32-lane inclusive suffix scan over q, both batches interleaved.
    float ia = Ga, ib = Gb;
    #pragma unroll
    for (int d = 1; d < 32; d <<= 1) {
        const float oa = __shfl_down(ia, d, 32);
        const float ob = __shfl_down(ib, d, 32);
        if (q + d < 32) { ia += oa; ib += ob; }
    }
    const float Tqa = ia - Ga;
    const float Tqb = ib - Gb;

    float pa = xsa * (Aa + Tqa * Wrsum + lw);
    float pb = xsb * (Ab + Tqb * Wrsum + lw);

    // Wave butterflies (interleaved), one partial per wave per batch.
    #pragma unroll
    for (int d = 32; d >= 1; d >>= 1) {
        pa += __shfl_xor(pa, d);
        pb += __shfl_xor(pb, d);
    }
    if ((t & 63) == 0) {
        red[0][t >> 6] = pa;
        red[1][t >> 6] = pb;
    }

    __syncthreads();   // single barrier for the reduction tail

    if (t < BPB) {
        float tot = red[t][0] + red[t][1] + red[t][2] + red[t][3]
                  + red[t][4] + red[t][5] + red[t][6] + red[t][7];
        tot += lin_b[0];
        out[b0 + t] = 1.0f / (1.0f + expf(-tot));
    }
}

extern "C" void kernel_launch(void* const* d_in, const int* in_sizes, int n_in,
                              void* d_out, int out_size, void* d_ws, size_t ws_size,
                              hipStream_t stream) {
    const float* x     = (const float*)d_in[0];
    const float* W     = (const float*)d_in[1];
    const float* lin_w = (const float*)d_in[2];
    const float* lin_b = (const float*)d_in[3];
    float* out = (float*)d_out;

    hipLaunchKernelGGL(fm_kernel, dim3(Bn / BPB), dim3(512), 0, stream,
                       x, W, lin_w, lin_b, out);
}